// Round 1
// 692.411 us; speedup vs baseline: 1.0450x; 1.0450x over previous
//
#include <hip/hip_runtime.h>
#include <hip/hip_bf16.h>
#include <cstdint>
#include <cstddef>

// Problem constants
#define E_   8
#define H_   2048
#define I_   2816
#define T_   512
#define NPAIR 1024         // T*K (token,k) pairs

// GEMM tiling
#define TM   192           // one m-tile per expert w.h.p. -> weights streamed once
#define TN   32
#define BK   64
#define LDSB 72            // padded LDS row stride (bf16): 144 B
#define MT_  3             // m-frags per wave (192 / 4 waves / 16)

typedef __attribute__((ext_vector_type(8))) short          bf16x8;
typedef __attribute__((ext_vector_type(4))) float          f32x4;
typedef __attribute__((ext_vector_type(8))) unsigned short u16x8;

__device__ __forceinline__ unsigned short f2bf(float f){
  union { float f; unsigned u; } a; a.f = f;
  unsigned u = a.u;
  unsigned r = u + 0x7fffu + ((u >> 16) & 1u);   // RNE
  return (unsigned short)(r >> 16);
}

// Pack 4 floats (x scale) to 4 bf16 via packed HW cvt where available
__device__ __forceinline__ void cvt4(u16x8& dst, int base, const float4 v, float s){
  __hip_bfloat162 p0 = __float22bfloat162_rn(float2{v.x*s, v.y*s});
  __hip_bfloat162 p1 = __float22bfloat162_rn(float2{v.z*s, v.w*s});
  union { __hip_bfloat162 b; unsigned u; } a0{p0}, a1{p1};
  dst[base+0] = (unsigned short)(a0.u & 0xffff);
  dst[base+1] = (unsigned short)(a0.u >> 16);
  dst[base+2] = (unsigned short)(a1.u & 0xffff);
  dst[base+3] = (unsigned short)(a1.u >> 16);
}

// LDS-only barrier: drain LDS ops, DO NOT drain vmcnt -> global prefetch
// loads stay in flight across the barrier (AITER/CK-style pipeline).
__device__ __forceinline__ void sync_lds(){
  asm volatile("s_waitcnt lgkmcnt(0)\n\ts_barrier" ::: "memory");
}

// ---------------------------------------------------------------------------
// Routing: bucket 1024 (t,k) pairs by expert; also inverse map slot-of-pair.
// ---------------------------------------------------------------------------
__global__ void route_kernel(const int* __restrict__ ids,
                             int* __restrict__ offs, int* __restrict__ ptok,
                             int* __restrict__ sop){
  __shared__ int scnt[E_];
  __shared__ int scur[E_];
  const int tid = threadIdx.x;
  if (tid < E_) scnt[tid] = 0;
  __syncthreads();
  const int e = ids[tid];
  atomicAdd(&scnt[e], 1);
  __syncthreads();
  if (tid == 0){
    int s = 0;
    for (int i = 0; i < E_; i++){ offs[i] = s; scur[i] = s; s += scnt[i]; }
    offs[E_] = s;
  }
  __syncthreads();
  const int pos = atomicAdd(&scur[e], 1);
  ptok[pos] = tid >> 1;
  sop[tid]  = pos;
}

// ---------------------------------------------------------------------------
// Prep: gather+convert x rows into slot order, bf16. xg[slot][H]
// ---------------------------------------------------------------------------
__global__ void prep_kernel(const float* __restrict__ x, const int* __restrict__ ptok,
                            unsigned short* __restrict__ xg){
  const int slot = blockIdx.x;
  const int tok  = ptok[slot];
  const int k0   = threadIdx.x * 8;
  const float4 v0 = *(const float4*)(x + (size_t)tok*H_ + k0);
  const float4 v1 = *(const float4*)(x + (size_t)tok*H_ + k0 + 4);
  u16x8 o;
  cvt4(o, 0, v0, 1.f);
  cvt4(o, 4, v1, 1.f);
  *(u16x8*)(xg + (size_t)slot*H_ + k0) = o;
}

// ---------------------------------------------------------------------------
// GEMM1: act[slot,i] = silu(x@Wg^T)*(x@Wu^T). B: global->reg prefetch
// distance 2 + LDS double-buffer (even tiles buf0, odd buf1); A: global
// direct, distance-1 reg prefetch. One LDS-only barrier per tile.
//
// XCD pinning: gridDim.x == 8 == #XCDs and blockIdx.x == expert, so the
// linear-round-robin workgroup->XCD dispatch puts ALL blocks of expert e on
// XCD e. Per-XCD A footprint (xg tile, <=768 KB) then fits the 4 MB L2 and
// is fetched from HBM once instead of once per nb-block.
// grid: (E=8, I/TN=88, 6), block 256.
// ---------------------------------------------------------------------------
__global__ __launch_bounds__(256, 3)
void gemm1_kernel(const unsigned short* __restrict__ xg, const float* __restrict__ w13,
                  const float* __restrict__ s13, const int* __restrict__ offs,
                  unsigned short* __restrict__ act)
{
  const int e   = blockIdx.x;
  const int off = offs[e];
  const int cnt = offs[e+1] - off;
  const int m0  = blockIdx.z * TM;
  if (m0 >= cnt) return;
  const int rows = min(TM, cnt - m0);
  const int nb   = blockIdx.y * TN;

  __shared__ __align__(16) unsigned short Bs[2][2*TN][LDSB];  // 18432 B

  const int tid  = threadIdx.x;
  const int wave = tid >> 6;
  const int lane = tid & 63;
  const int quad = lane >> 4;
  const int l16  = lane & 15;

  const float* w13e = w13 + (size_t)e * (2*I_) * H_;
  const float* s13e = s13 + (size_t)e * (2*I_/128) * (H_/128);

  // B staging: row br (0..63: gate 0..31, up 32..63), 4 threads/row, 16 floats
  const int br = tid >> 2;
  const int bc = tid & 3;
  const int grow = (br < TN) ? (nb + br) : (I_ + nb + (br - TN));
  const float* bp = w13e + (size_t)grow * H_ + bc*16;
  const int srow  = (((br < TN) ? 0 : (I_/128)) + (nb >> 7)) * (H_/128);

  // A fragment row pointers (clamped; OOB rows discarded in epilogue)
  const unsigned short* aP[MT_];
  #pragma unroll
  for (int mt = 0; mt < MT_; mt++){
    int sl = off + m0 + wave*(TM/4) + mt*16 + l16;
    sl = min(sl, NPAIR - 1);
    aP[mt] = xg + (size_t)sl * H_ + quad*8;
  }

  f32x4 acc[2][MT_][2];
  #pragma unroll
  for (int h = 0; h < 2; h++)
    #pragma unroll
    for (int mt = 0; mt < MT_; mt++)
      #pragma unroll
      for (int nt = 0; nt < 2; nt++)
        acc[h][mt][nt] = (f32x4){0.f, 0.f, 0.f, 0.f};

  float4 R0[4], R1[4];        // B reg buffers (tiles i+1, i+2)
  bf16x8 A0[2][MT_], A1[2][MT_];
  float  sE, sO;

  auto loadB = [&](int t, float4* R){
    const float* p = bp + t*BK;
    #pragma unroll
    for (int j = 0; j < 4; j++) R[j] = *(const float4*)(p + j*4);
  };
  auto loadA = [&](int t, bf16x8 (*A)[MT_]){
    #pragma unroll
    for (int kk = 0; kk < 2; kk++)
      #pragma unroll
      for (int mt = 0; mt < MT_; mt++)
        A[kk][mt] = *(const bf16x8*)(aP[mt] + t*BK + kk*32);
  };
  auto storeB = [&](const float4* R, float s, int buf){
    u16x8 w0, w1;
    cvt4(w0, 0, R[0], s); cvt4(w0, 4, R[1], s);
    cvt4(w1, 0, R[2], s); cvt4(w1, 4, R[3], s);
    *(u16x8*)&Bs[buf][br][bc*16]     = w0;
    *(u16x8*)&Bs[buf][br][bc*16 + 8] = w1;
  };
  auto mfma = [&](int buf, bf16x8 (*A)[MT_]){
    #pragma unroll
    for (int kk = 0; kk < 2; kk++)
      #pragma unroll
      for (int hh = 0; hh < 2; hh++)
        #pragma unroll
        for (int nt = 0; nt < 2; nt++){
          bf16x8 bv = *(const bf16x8*)&Bs[buf][hh*TN + nt*16 + l16][kk*32 + quad*8];
          #pragma unroll
          for (int mt = 0; mt < MT_; mt++)
            acc[hh][mt][nt] = __builtin_amdgcn_mfma_f32_16x16x32_bf16(A[kk][mt], bv, acc[hh][mt][nt], 0, 0, 0);
        }
  };

  const int NITER = H_/BK;   // 32 (even)
  // prologue
  loadB(0, R0); sE = s13e[srow];
  loadB(1, R1); sO = s13e[srow];
  loadA(0, A0);
  storeB(R0, sE, 0);
  sync_lds();

  for (int i = 0; i < NITER; i += 2){
    if (i+2 < NITER){ loadB(i+2, R0); sE = s13e[srow + ((i+2) >> 1)]; }
    loadA(i+1, A1);
    mfma(0, A0);
    storeB(R1, sO, 1);
    sync_lds();
    if (i+3 < NITER){ loadB(i+3, R1); sO = s13e[srow + ((i+3) >> 1)]; }
    if (i+2 < NITER) loadA(i+2, A0);
    mfma(1, A1);
    if (i+2 < NITER){ storeB(R0, sE, 0); sync_lds(); }
  }

  // epilogue: act = silu(gate)*up
  #pragma unroll
  for (int mt = 0; mt < MT_; mt++){
    #pragma unroll
    for (int nt = 0; nt < 2; nt++){
      #pragma unroll
      for (int r = 0; r < 4; r++){
        const int m = wave*(TM/4) + mt*16 + quad*4 + r;
        if (m < rows){
          const float g = acc[0][mt][nt][r];
          const float u = acc[1][mt][nt][r];
          const float sg = g / (1.f + __expf(-g));
          act[(size_t)(off + m0 + m)*I_ + (nb + nt*16 + l16)] = f2bf(sg * u);
        }
      }
    }
  }
}

// ---------------------------------------------------------------------------
// GEMM2: buf[slot,h] = act @ W2^T (unscaled). Same pipeline.
// XCD pinning as gemm1: blockIdx.x == expert -> expert e on XCD e; the act
// tile written by gemm1 on the same XCD is likely still L2-resident.
// grid: (E=8, H/TN=64, 6), block 256.
// ---------------------------------------------------------------------------
__global__ __launch_bounds__(256, 3)
void gemm2_kernel(const unsigned short* __restrict__ act, const float* __restrict__ w2,
                  const float* __restrict__ s2, const int* __restrict__ offs,
                  float* __restrict__ buf)
{
  const int e   = blockIdx.x;
  const int off = offs[e];
  const int cnt = offs[e+1] - off;
  const int m0  = blockIdx.z * TM;
  if (m0 >= cnt) return;
  const int rows = min(TM, cnt - m0);
  const int nb   = blockIdx.y * TN;

  __shared__ __align__(16) unsigned short Bs[2][TN][LDSB];   // 9216 B

  const int tid  = threadIdx.x;
  const int wave = tid >> 6;
  const int lane = tid & 63;
  const int quad = lane >> 4;
  const int l16  = lane & 15;

  const float* w2e = w2 + (size_t)e * H_ * I_;
  const float* s2e = s2 + (size_t)e * (H_/128) * (I_/128);

  // B staging: 8 threads/row, 8 contiguous floats each
  const int br = tid >> 3;                // 0..31
  const int bc = tid & 7;
  const float* bp = w2e + (size_t)(nb + br) * I_ + bc*8;
  const int srow  = (nb >> 7) * (I_/128);

  const unsigned short* aP[MT_];
  #pragma unroll
  for (int mt = 0; mt < MT_; mt++){
    int sl = off + m0 + wave*(TM/4) + mt*16 + l16;
    sl = min(sl, NPAIR - 1);
    aP[mt] = act + (size_t)sl * I_ + quad*8;
  }

  f32x4 acc[MT_][2];
  #pragma unroll
  for (int mt = 0; mt < MT_; mt++)
    #pragma unroll
    for (int nt = 0; nt < 2; nt++)
      acc[mt][nt] = (f32x4){0.f, 0.f, 0.f, 0.f};

  float4 R0[2], R1[2];
  bf16x8 A0[2][MT_], A1[2][MT_];
  float  sE, sO;

  auto loadB = [&](int t, float4* R){
    const float* p = bp + t*BK;
    #pragma unroll
    for (int j = 0; j < 2; j++) R[j] = *(const float4*)(p + j*4);
  };
  auto loadA = [&](int t, bf16x8 (*A)[MT_]){
    #pragma unroll
    for (int kk = 0; kk < 2; kk++)
      #pragma unroll
      for (int mt = 0; mt < MT_; mt++)
        A[kk][mt] = *(const bf16x8*)(aP[mt] + t*BK + kk*32);
  };
  auto storeB = [&](const float4* R, float s, int buf_i){
    u16x8 w0;
    cvt4(w0, 0, R[0], s); cvt4(w0, 4, R[1], s);
    *(u16x8*)&Bs[buf_i][br][bc*8] = w0;
  };
  auto mfma = [&](int buf_i, bf16x8 (*A)[MT_]){
    #pragma unroll
    for (int kk = 0; kk < 2; kk++)
      #pragma unroll
      for (int nt = 0; nt < 2; nt++){
        bf16x8 bv = *(const bf16x8*)&Bs[buf_i][nt*16 + l16][kk*32 + quad*8];
        #pragma unroll
        for (int mt = 0; mt < MT_; mt++)
          acc[mt][nt] = __builtin_amdgcn_mfma_f32_16x16x32_bf16(A[kk][mt], bv, acc[mt][nt], 0, 0, 0);
      }
  };

  const int NITER = I_/BK;   // 44 (even)
  loadB(0, R0); sE = s2e[srow];
  loadB(1, R1); sO = s2e[srow];
  loadA(0, A0);
  storeB(R0, sE, 0);
  sync_lds();

  for (int i = 0; i < NITER; i += 2){
    if (i+2 < NITER){ loadB(i+2, R0); sE = s2e[srow + ((i+2) >> 1)]; }
    loadA(i+1, A1);
    mfma(0, A0);
    storeB(R1, sO, 1);
    sync_lds();
    if (i+3 < NITER){ loadB(i+3, R1); sO = s2e[srow + ((i+3) >> 1)]; }
    if (i+2 < NITER) loadA(i+2, A0);
    mfma(1, A1);
    if (i+2 < NITER){ storeB(R0, sE, 0); sync_lds(); }
  }

  // epilogue: plain stores per slot row
  #pragma unroll
  for (int mt = 0; mt < MT_; mt++){
    #pragma unroll
    for (int nt = 0; nt < 2; nt++){
      #pragma unroll
      for (int r = 0; r < 4; r++){
        const int m = wave*(TM/4) + mt*16 + quad*4 + r;
        if (m < rows)
          buf[(size_t)(off + m0 + m)*H_ + (nb + nt*16 + l16)] = acc[mt][nt][r];
      }
    }
  }
}

// ---------------------------------------------------------------------------
// Combine: out[t,:] = tw[2t]*buf[sop[2t],:] + tw[2t+1]*buf[sop[2t+1],:]
// ---------------------------------------------------------------------------
__global__ void combine_kernel(const float* __restrict__ buf, const int* __restrict__ sop,
                               const float* __restrict__ tw, float* __restrict__ out){
  const int gid = blockIdx.x*256 + threadIdx.x;
  const int t = gid >> 9;
  const int c = gid & 511;
  const int s0 = sop[2*t], s1 = sop[2*t+1];
  const float w0 = tw[2*t], w1 = tw[2*t+1];
  const float4 v0 = ((const float4*)buf)[(size_t)s0*(H_/4) + c];
  const float4 v1 = ((const float4*)buf)[(size_t)s1*(H_/4) + c];
  float4 o;
  o.x = w0*v0.x + w1*v1.x;
  o.y = w0*v0.y + w1*v1.y;
  o.z = w0*v0.z + w1*v1.z;
  o.w = w0*v0.w + w1*v1.w;
  ((float4*)out)[gid] = o;
}

// ---------------------------------------------------------------------------
extern "C" void kernel_launch(void* const* d_in, const int* in_sizes, int n_in,
                              void* d_out, int out_size, void* d_ws, size_t ws_size,
                              hipStream_t stream){
  const float* x   = (const float*)d_in[0];
  const int*   ids = (const int*)  d_in[1];
  const float* tw  = (const float*)d_in[2];
  const float* w13 = (const float*)d_in[3];
  const float* s13 = (const float*)d_in[4];
  const float* w2  = (const float*)d_in[5];
  const float* s2  = (const float*)d_in[6];
  float* out = (float*)d_out;

  char* ws = (char*)d_ws;
  int* offs = (int*)ws;                                   // 9 ints
  int* ptok = (int*)(ws + 64);                            // 1024 ints
  int* sop  = (int*)(ws + 64 + 4096);                     // 1024 ints
  unsigned short* xg  = (unsigned short*)(ws + 16384);    // [1024][H] bf16 (aliased by buf)
  float*          buf = (float*)(ws + 16384);             // [1024][H] f32
  unsigned short* act = (unsigned short*)(ws + 16384 + (size_t)NPAIR*H_*4);  // [1024][I] bf16

  route_kernel  <<<1, NPAIR, 0, stream>>>(ids, offs, ptok, sop);
  prep_kernel   <<<NPAIR, 256, 0, stream>>>(x, ptok, xg);
  gemm1_kernel  <<<dim3(E_, I_/TN, (NPAIR + TM - 1)/TM), 256, 0, stream>>>(xg, w13, s13, offs, act);
  gemm2_kernel  <<<dim3(E_, H_/TN, (NPAIR + TM - 1)/TM), 256, 0, stream>>>(act, w2, s2, offs, buf);
  combine_kernel<<<(T_*H_/4)/256, 256, 0, stream>>>(buf, sop, tw, out);
}